// Round 12
// baseline (349.092 us; speedup 1.0000x reference)
//
#include <hip/hip_runtime.h>
#include <math.h>

typedef __attribute__((ext_vector_type(4))) float f4;
typedef __attribute__((ext_vector_type(8))) short s8v;   // bf16x8 MFMA fragment
typedef __attribute__((ext_vector_type(4))) unsigned int u4v;
typedef __attribute__((ext_vector_type(2))) unsigned int u2v;

#define NVOX 262144        // 64^3
#define MB_TOT 67108864    // 4*64*NVOX

__device__ __forceinline__ float sigm(float x){ return 1.0f/(1.0f+expf(-x)); }
__device__ __forceinline__ unsigned short f2b(float f){
  unsigned x = __float_as_uint(f);
  return (unsigned short)((x + 0x7fffu + ((x>>16)&1u)) >> 16);
}
__device__ __forceinline__ unsigned cvtpk(float lo, float hi){
  unsigned r;
  asm("v_cvt_pk_bf16_f32 %0, %1, %2" : "=v"(r) : "v"(lo), "v"(hi));
  return r;
}
__device__ __forceinline__ float bl(unsigned u){ return __uint_as_float(u<<16); }
__device__ __forceinline__ float bh(unsigned u){ return __uint_as_float(u & 0xffff0000u); }

// ---------------- pass 1 (NEW): pass3-staging clone + butterfly reduce -> partials ----------
// 4096 blocks x 256 threads; block = z-row tile (i=b>>6, j=b&63 BLOCK-UNIFORM), wave = modality.
// Load pattern IDENTICAL to pass3's staging (16 back-to-back f4 loads, 1MB stride, 16KB/wave
// in flight — the structure measured at ~5.5 TB/s). Per row: per-lane static z-hat weights,
// 16-lane shfl_xor reduce -> {S0..3 (z16-bucket sums), W0..3 (z-hat sums)} per (mc, tile);
// lane r==0 stores 32B to partial[mc][tile][8]. i/j hat application deferred to pass1b.
__global__ __launch_bounds__(256) void k_pass1(const float* __restrict__ x,
                                               float* __restrict__ partial){
  int tid = threadIdx.x;
  int b = blockIdx.x;
  size_t V0 = (size_t)b * 64;
  int m = tid >> 6;
  int lane = tid & 63;
  int ks = lane >> 4, r = lane & 15;
  // per-lane z weights (z = r*4+e); lzc uniform within the quad (knots 8/24/40/56 are quad-aligned)
  int z0 = r*4;
  int lzc = (z0<8)?0:((z0>=56)?3:((z0-8)>>4));
  float wq0 = (z0  <8||z0  >=56)?0.f:((z0+0.5f)*0.0625f-0.5f-(float)lzc);
  float wq1 = (z0+1<8||z0+1>=56)?0.f:((z0+1.5f)*0.0625f-0.5f-(float)lzc);
  float wq2 = (z0+2<8||z0+2>=56)?0.f:((z0+2.5f)*0.0625f-0.5f-(float)lzc);
  float wq3 = (z0+3<8||z0+3>=56)?0.f:((z0+3.5f)*0.0625f-0.5f-(float)lzc);
  float m0A = (lzc==0)?1.f:0.f, m1A = (lzc==1)?1.f:0.f, m2A=(lzc==2)?1.f:0.f, m3A=(lzc==3)?1.f:0.f;
  float m1B = (lzc==0)?1.f:0.f, m2B = (lzc==1)?1.f:0.f, m3B=(lzc==2)?1.f:0.f;  // lzc==3 -> wB==0
  const float* xw = x + (size_t)(m*64)*NVOX + V0 + r*4;
  f4 v[16];
#pragma unroll
  for (int rr=0; rr<16; ++rr)
    v[rr] = *reinterpret_cast<const f4*>(xw + (size_t)(ks*16+rr)*NVOX);
  float* ob = partial + ((size_t)(m*64)*4096 + b)*8;
#pragma unroll
  for (int rr=0; rr<16; ++rr){
    f4 u = v[rr];
    float s  = (u.x+u.y)+(u.z+u.w);
    float wB = u.x*wq0 + u.y*wq1 + u.z*wq2 + u.w*wq3;
    float wA = s - wB;
    float w0 = m0A*wA;
    float w1 = m1A*wA + m1B*wB;
    float w2 = m2A*wA + m2B*wB;
    float w3 = m3A*wA + m3B*wB;
#pragma unroll
    for (int mk=1; mk<16; mk<<=1){
      w0 += __shfl_xor(w0, mk, 16);
      w1 += __shfl_xor(w1, mk, 16);
      w2 += __shfl_xor(w2, mk, 16);
      w3 += __shfl_xor(w3, mk, 16);
    }
    float sg = s + __shfl_xor(s, 1, 4);
    sg += __shfl_xor(sg, 2, 4);
    float s1 = __shfl(sg, 4, 16);
    float s2 = __shfl(sg, 8, 16);
    float s3 = __shfl(sg, 12, 16);
    if (r == 0){
      int cc = ks*16 + rr;
      f4 A; A.x=sg; A.y=s1; A.z=s2; A.w=s3;
      f4 B; B.x=w0; B.y=w1; B.z=w2; B.w=w3;
      f4* op = reinterpret_cast<f4*>(ob + (size_t)cc*4096*8);
      op[0] = A; op[1] = B;
    }
  }
}

// ---------------- pass 1b: reduce partials over tiles, apply i/j hats ----------------
// 256 blocks (one per mc) x 256 threads; thread reads 16 tiles x 32B coalesced.
// j is constant per thread (tiles t = tid + 256s keep t&63 fixed) -> j-hat hoisted.
__global__ __launch_bounds__(256) void k_pass1b(const float* __restrict__ partial,
                                                float* __restrict__ dsums,
                                                float* __restrict__ xbsums){
  __shared__ float xbL[64];
  __shared__ float bsL[64];
  int tid = threadIdx.x;
  int mc = blockIdx.x;
  if (tid < 64){ xbL[tid]=0.f; bsL[tid]=0.f; }
  __syncthreads();
  int j = tid & 63;
  float cj = fminf(fmaxf((j+0.5f)*0.0625f-0.5f, 0.f), 3.f);
  int lj = (int)cj; float wj = cj - (float)lj; int hj = lj<3?lj+1:3;
  float cjA = 1.f - wj, cjB = wj;
  int jq = j >> 4;
  int i0 = tid >> 6;
#pragma unroll
  for (int s=0; s<16; ++s){
    int i = i0 + s*4;
    int t = tid + s*256;
    const f4* pp = reinterpret_cast<const f4*>(partial + ((size_t)mc*4096 + t)*8);
    f4 S = pp[0];
    f4 W = pp[1];
    int iq = i >> 4;
    int bb = iq*16 + jq*4;
    atomicAdd(&bsL[bb+0], S.x);
    atomicAdd(&bsL[bb+1], S.y);
    atomicAdd(&bsL[bb+2], S.z);
    atomicAdd(&bsL[bb+3], S.w);
    float ci = fminf(fmaxf((i+0.5f)*0.0625f-0.5f, 0.f), 3.f);
    int li = (int)ci; float wi = ci - (float)li; int hi = li<3?li+1:3;
    float c00 = (1.f-wi)*cjA, c01 = (1.f-wi)*cjB, c10 = wi*cjA, c11 = wi*cjB;
#pragma unroll
    for (int p=0; p<4; ++p){
      float vv = W[p];
      atomicAdd(&xbL[li*16+lj*4+p], c00*vv);
      atomicAdd(&xbL[li*16+hj*4+p], c01*vv);
      atomicAdd(&xbL[hi*16+lj*4+p], c10*vv);
      atomicAdd(&xbL[hi*16+hj*4+p], c11*vv);
    }
  }
  __syncthreads();
  if (tid < 64){
    dsums [(size_t)mc*64 + tid] = bsL[tid];
    xbsums[(size_t)mc*64 + tid] = xbL[tid];
  }
}

// ---------------- pass 1 fallback (r11): used only if ws too small for partials ----------
#define LDI(I) (*reinterpret_cast<const f4*>(xp + (size_t)((I)*64 + j)*64 + chunk*4))
#define BODY(I, V) { \
  float s_ = ((V).x+(V).y)+((V).z+(V).w); \
  float wB_ = (V).x*wqz0 + (V).y*wqz1 + (V).z*wqz2 + (V).w*wqz3; \
  float wA_ = s_ - wB_; \
  bacc += s_; \
  const int   li_  = ((I)<8)?0:(((I)>=56)?3:(((I)-8)>>4)); \
  const float wi_  = ((I)<8||(I)>=56)?0.0f:(((I)+0.5f)*0.0625f-0.5f-(float)li_); \
  const float h0_ = (li_==0)?(1.0f-wi_):0.0f; \
  const float h1_ = (li_==1)?(1.0f-wi_):((li_==0)?wi_:0.0f); \
  const float h2_ = (li_==2)?(1.0f-wi_):((li_==1)?wi_:0.0f); \
  const float h3_ = (li_==3)?(1.0f-wi_):((li_==2)?wi_:0.0f); \
  float eA_ = cjA*wA_, eB_ = cjA*wB_, fA_ = cjB*wA_, fB_ = cjB*wB_; \
  if (h0_ != 0.0f){ a0A0 += h0_*eA_; a0A1 += h0_*eB_; a0B0 += h0_*fA_; a0B1 += h0_*fB_; } \
  if (h1_ != 0.0f){ a1A0 += h1_*eA_; a1A1 += h1_*eB_; a1B0 += h1_*fA_; a1B1 += h1_*fB_; } \
  if (h2_ != 0.0f){ a2A0 += h2_*eA_; a2A1 += h2_*eB_; a2B0 += h2_*fA_; a2B1 += h2_*fB_; } \
  if (h3_ != 0.0f){ a3A0 += h3_*eA_; a3A1 += h3_*eB_; a3B0 += h3_*fA_; a3B1 += h3_*fB_; } \
}
#define IBLK(I0) \
  _Pragma("unroll") \
  for (int it=0; it<16; it+=4){ \
    f4 v0_ = LDI((I0)+it+0); \
    f4 v1_ = LDI((I0)+it+1); \
    f4 v2_ = LDI((I0)+it+2); \
    f4 v3_ = LDI((I0)+it+3); \
    BODY((I0)+it+0, v0_); \
    BODY((I0)+it+1, v1_); \
    BODY((I0)+it+2, v2_); \
    BODY((I0)+it+3, v3_); \
  }

__global__ __launch_bounds__(256) void k_pass1_old(const float* __restrict__ x,
                                                   float* __restrict__ dsums,
                                                   float* __restrict__ xbsums){
  __shared__ float xbL[64];
  __shared__ float bsL[64];
  int tid = threadIdx.x;
  int b = blockIdx.x;
  int mc = b >> 4;
  int jh = (b >> 2) & 3;
  int ib = b & 3;
  if (tid < 64){ xbL[tid]=0.f; bsL[tid]=0.f; }
  __syncthreads();
  const float* xp = x + (size_t)mc * NVOX;
  int chunk = tid & 15;
  int jslot = tid >> 4;
  int j = jh*16 + jslot;
  float wqz0,wqz1,wqz2,wqz3;
  {
    int z0 = chunk*4;
    int lzc0 = (z0<8)?0:((z0>=56)?3:((z0-8)>>4));
    wqz0 = (z0  <8||z0  >=56)?0.0f:((z0+0.5f)*0.0625f-0.5f-(float)lzc0);
    wqz1 = (z0+1<8||z0+1>=56)?0.0f:((z0+1.5f)*0.0625f-0.5f-(float)lzc0);
    wqz2 = (z0+2<8||z0+2>=56)?0.0f:((z0+2.5f)*0.0625f-0.5f-(float)lzc0);
    wqz3 = (z0+3<8||z0+3>=56)?0.0f:((z0+3.5f)*0.0625f-0.5f-(float)lzc0);
  }
  int lzc = (chunk*4<8)?0:((chunk*4>=56)?3:((chunk*4-8)>>4));
  int kq = chunk >> 2;
  float cjA, cjB; int lj;
  {
    float cj = fminf(fmaxf((j+0.5f)*0.0625f-0.5f, 0.0f), 3.0f);
    lj = (int)cj; float wj = cj - (float)lj;
    cjA = 1.0f - wj; cjB = wj;
  }
  float a0A0=0.f,a0A1=0.f,a0B0=0.f,a0B1=0.f;
  float a1A0=0.f,a1A1=0.f,a1B0=0.f,a1B1=0.f;
  float a2A0=0.f,a2A1=0.f,a2B0=0.f,a2B1=0.f;
  float a3A0=0.f,a3A1=0.f,a3B0=0.f,a3B1=0.f;
  float bacc=0.f;
  if      (ib == 0){ IBLK(0)  }
  else if (ib == 1){ IBLK(16) }
  else if (ib == 2){ IBLK(32) }
  else             { IBLK(48) }
  {
    int p00 = lj*4 + lzc;
    atomicAdd(&xbL[ 0 + p00], a0A0);
    atomicAdd(&xbL[16 + p00], a1A0);
    atomicAdd(&xbL[32 + p00], a2A0);
    atomicAdd(&xbL[48 + p00], a3A0);
    if (lzc < 3){
      atomicAdd(&xbL[ 0 + p00+1], a0A1);
      atomicAdd(&xbL[16 + p00+1], a1A1);
      atomicAdd(&xbL[32 + p00+1], a2A1);
      atomicAdd(&xbL[48 + p00+1], a3A1);
    }
    if (lj < 3){
      atomicAdd(&xbL[ 0 + p00+4], a0B0);
      atomicAdd(&xbL[16 + p00+4], a1B0);
      atomicAdd(&xbL[32 + p00+4], a2B0);
      atomicAdd(&xbL[48 + p00+4], a3B0);
      if (lzc < 3){
        atomicAdd(&xbL[ 0 + p00+5], a0B1);
        atomicAdd(&xbL[16 + p00+5], a1B1);
        atomicAdd(&xbL[32 + p00+5], a2B1);
        atomicAdd(&xbL[48 + p00+5], a3B1);
      }
    }
    atomicAdd(&bsL[ib*16 + jh*4 + kq], bacc);
  }
  __syncthreads();
  if (tid < 64){
    atomicAdd(&xbsums[(size_t)mc*64 + tid], xbL[tid]);
    atomicAdd(&dsums [(size_t)mc*64 + tid], bsL[tid]);
  }
}

// ---------------- pass 2: all tiny MLPs (single block) + wf->bf16 conversion ----------------
__global__ __launch_bounds__(256) void k_pass2(
    const float* __restrict__ dsums, const float* __restrict__ xbsums,
    const float* __restrict__ wq1, const float* __restrict__ bq1,
    const float* __restrict__ wq2, const float* __restrict__ bq2,
    const float* __restrict__ wa1, const float* __restrict__ ba1,
    const float* __restrict__ wa2, const float* __restrict__ ba2,
    const float* __restrict__ wf,  const float* __restrict__ bfv,
    const float* __restrict__ wg1, const float* __restrict__ bg1,
    const float* __restrict__ wg2, const float* __restrict__ bg2,
    float* __restrict__ wsa, float* __restrict__ wsgate,
    float* __restrict__ wsqw, float* __restrict__ wsinv,
    unsigned short* __restrict__ wfb,
    float* __restrict__ outp)
{
  __shared__ float sGap[256];
  __shared__ float sA[256];
  __shared__ float sCm[256];
  __shared__ float sG[256];
  __shared__ float sGG[16];
  __shared__ float sQw[4];
  int tid = threadIdx.x;
  int m = tid>>6, c = tid&63;
  for (int t = tid; t < 4096; t += 256) wfb[t] = f2b(wf[t]);
  {
    float s=0.f;
    const float* dp = dsums + (size_t)tid*64;
    for (int p=0;p<64;++p) s += dp[p];
    sGap[tid] = s * (1.0f/262144.0f);
  }
  {
    int p = c;
    float h0=0,h1=0,h2=0,h3=0;
    for (int cc=0; cc<64; ++cc){
      float dm = dsums[((size_t)(m*64+cc))*64+p] * (1.0f/4096.0f);
      h0 += dm * wa1[0*64+cc];
      h1 += dm * wa1[1*64+cc];
      h2 += dm * wa1[2*64+cc];
      h3 += dm * wa1[3*64+cc];
    }
    h0 = fmaxf(h0 + ba1[0], 0.f);
    h1 = fmaxf(h1 + ba1[1], 0.f);
    h2 = fmaxf(h2 + ba1[2], 0.f);
    h3 = fmaxf(h3 + ba1[3], 0.f);
    float s = h0*wa2[0] + h1*wa2[1] + h2*wa2[2] + h3*wa2[3] + ba2[0];
    float aa = sigm(s);
    sA[tid] = aa;
    wsa[tid] = aa;
  }
  __syncthreads();
  if (tid < 4){
    int mm = tid;
    float q0=0,q1=0,q2=0,q3=0;
    for (int cc=0; cc<64; ++cc){
      float g = sGap[mm*64+cc];
      q0 += g*wq1[0*64+cc];
      q1 += g*wq1[1*64+cc];
      q2 += g*wq1[2*64+cc];
      q3 += g*wq1[3*64+cc];
    }
    q0 = fmaxf(q0+bq1[0],0.f); q1 = fmaxf(q1+bq1[1],0.f);
    q2 = fmaxf(q2+bq1[2],0.f); q3 = fmaxf(q3+bq1[3],0.f);
    float s0 = sigm(q0*wq2[0]+q1*wq2[1]+q2*wq2[2]+q3*wq2[3]+bq2[0]);
    float s1 = sigm(q0*wq2[4]+q1*wq2[5]+q2*wq2[6]+q3*wq2[7]+bq2[1]);
    sQw[mm] = 0.5f*(s0+s1);
    outp[MB_TOT + mm]     = s0;  // boundary
    outp[MB_TOT + 4 + mm] = s1;  // semantic
  }
  __syncthreads();
  float qw_m = sQw[m];
  float T = sQw[0]+sQw[1]+sQw[2]+sQw[3];
  float inv_m = 1.0f/(T - qw_m);
  if (tid < 4){ wsqw[tid] = sQw[tid]; wsinv[tid] = 1.0f/(T - sQw[tid]); }
  {
    const float* xbp = xbsums + (size_t)tid*64;
    float s=0.f;
    for (int p=0;p<64;++p) s += sA[m*64+p]*xbp[p];
    sCm[tid] = qw_m * s * (1.0f/262144.0f);
  }
  __syncthreads();
  {
    int dd = c;
    float acc=0.f;
    for (int cc=0; cc<64; ++cc){
      float Sm = sCm[0*64+cc]+sCm[1*64+cc]+sCm[2*64+cc]+sCm[3*64+cc];
      float em = (Sm - sCm[m*64+cc]) * inv_m;
      acc += em * wf[dd*64+cc];
    }
    sG[tid] = acc + bfv[dd];
  }
  __syncthreads();
  if (tid < 16){
    int mm = tid>>2, k = tid&3;
    float acc=0.f;
    for (int dd=0; dd<64; ++dd) acc += sG[mm*64+dd]*wg1[k*64+dd];
    sGG[tid] = fmaxf(acc + bg1[k], 0.f);
  }
  __syncthreads();
  {
    float s = sGG[m*4+0]*wg2[c*4+0] + sGG[m*4+1]*wg2[c*4+1]
            + sGG[m*4+2]*wg2[c*4+2] + sGG[m*4+3]*wg2[c*4+3] + bg2[c];
    wsgate[tid] = sigm(s);
  }
}

// ---------------- pass 3: coalesced fp32 staging + MFMA + coalesced transposed store ----------
__global__ __launch_bounds__(256) void k_pass3(
    const float* __restrict__ x, const unsigned short* __restrict__ wfb,
    const float* __restrict__ bfv,
    const float* __restrict__ wsa, const float* __restrict__ wsgate,
    const float* __restrict__ wsqw, const float* __restrict__ wsinv,
    float* __restrict__ outp)
{
  __shared__ unsigned int xt[4][32][68];
  __shared__ unsigned int fusedT[64][34];
  __shared__ float aCell[4][64];
  __shared__ float gateL[4][64];
  __shared__ __align__(16) float auq[4][64];
  __shared__ float bfL[64];
  __shared__ float A2[4][4];
  int tid = threadIdx.x;
  int b = 4095 - (int)blockIdx.x;     // reversed tile order (L3 reuse from pass1)
  int i = b >> 6, j = b & 63;
  size_t V0 = (size_t)b * 64;
  int w    = tid >> 6;
  int lane = tid & 63;
  int ks   = lane >> 4;
  int r    = lane & 15;
  int vox16 = w << 4;

  const float* xw = x + (size_t)(w*64)*NVOX + V0 + r*4;
  f4 v[16];
#pragma unroll
  for (int rr=0; rr<16; ++rr){
    int cc = ks*16 + rr;
    v[rr] = *reinterpret_cast<const f4*>(xw + (size_t)cc*NVOX);
  }
  aCell[w][lane] = wsa[tid];
  gateL[w][lane] = wsgate[tid];
  if (tid < 64) bfL[tid] = bfv[tid];
#pragma unroll
  for (int rr=0; rr<16; rr+=2){
    u4v pk;
#pragma unroll
    for (int q=0;q<4;++q) pk[q] = cvtpk(v[rr][q], v[rr+1][q]);
    *reinterpret_cast<u4v*>(&xt[w][ks*8 + (rr>>1)][r*4]) = pk;
  }
  __syncthreads();

  if (tid < 16){
    int mm = tid>>2, pz = tid&3;
    float ci = fminf(fmaxf((i+0.5f)*0.0625f-0.5f,0.f),3.f);
    int li=(int)ci; float wi=ci-(float)li; int hiI=li<3?li+1:3;
    float cj = fminf(fmaxf((j+0.5f)*0.0625f-0.5f,0.f),3.f);
    int lj=(int)cj; float wj=cj-(float)lj; int hj=lj<3?lj+1:3;
    A2[mm][pz] = (1.f-wi)*((1.f-wj)*aCell[mm][li*16+lj*4+pz] + wj*aCell[mm][li*16+hj*4+pz])
               + wi*((1.f-wj)*aCell[mm][hiI*16+lj*4+pz] + wj*aCell[mm][hiI*16+hj*4+pz]);
  }
  __syncthreads();
  {
    int mm = tid>>6, z = tid&63;
    float cz = fminf(fmaxf((z+0.5f)*0.0625f-0.5f,0.f),3.f);
    int lz=(int)cz; float wzf=cz-(float)lz; int hz=lz<3?lz+1:3;
    auq[mm][z] = ((1.f-wzf)*A2[mm][lz] + wzf*A2[mm][hz]) * wsqw[mm];
  }
  __syncthreads();

  s8v bfr[4][2];
#pragma unroll
  for (int t=0;t<4;++t)
#pragma unroll
    for (int kk=0;kk<2;++kk)
      bfr[t][kk] = *reinterpret_cast<const s8v*>(&wfb[(t*16 + r)*64 + kk*32 + ks*8]);

  f4 acc[4][4];
#pragma unroll
  for (int mm=0;mm<4;++mm)
#pragma unroll
    for (int t=0;t<4;++t) acc[mm][t] = f4{0.f,0.f,0.f,0.f};

#pragma unroll
  for (int mm=0;mm<4;++mm){
    union { unsigned int u[4]; s8v s; } A0, A1;
#pragma unroll
    for (int q=0;q<4;++q){
      A0.u[q] = xt[mm][ks*4+q][vox16+r];
      A1.u[q] = xt[mm][16+ks*4+q][vox16+r];
    }
#pragma unroll
    for (int t=0;t<4;++t){
      acc[mm][t] = __builtin_amdgcn_mfma_f32_16x16x32_bf16(A0.s, bfr[t][0], acc[mm][t], 0,0,0);
      acc[mm][t] = __builtin_amdgcn_mfma_f32_16x16x32_bf16(A1.s, bfr[t][1], acc[mm][t], 0,0,0);
    }
  }

  f4 aq[4]; float invv[4];
#pragma unroll
  for (int mm=0;mm<4;++mm){
    aq[mm]  = *reinterpret_cast<const f4*>(&auq[mm][vox16 + 4*ks]);
    invv[mm] = wsinv[mm];
  }
  f4 FS[4];
#pragma unroll
  for (int t=0;t<4;++t){
    FS[t] = f4{0.f,0.f,0.f,0.f};
#pragma unroll
    for (int mm=0;mm<4;++mm)
#pragma unroll
      for (int q=0;q<4;++q) FS[t][q] += aq[mm][q]*acc[mm][t][q];
  }

  int g4 = tid >> 4;
  int r4l = tid & 15;
#pragma unroll
  for (int mm=0;mm<4;++mm){
#pragma unroll
    for (int t=0;t<4;++t){
      int dd = t*16 + r;
      float bfvv = bfL[dd];
      float f0 = (FS[t][0] - aq[mm][0]*acc[mm][t][0])*invv[mm] + bfvv;
      float f1 = (FS[t][1] - aq[mm][1]*acc[mm][t][1])*invv[mm] + bfvv;
      float f2 = (FS[t][2] - aq[mm][2]*acc[mm][t][2])*invv[mm] + bfvv;
      float f3 = (FS[t][3] - aq[mm][3]*acc[mm][t][3])*invv[mm] + bfvv;
      u2v pk2;
      pk2.x = cvtpk(f0, f1);
      pk2.y = cvtpk(f2, f3);
      *reinterpret_cast<u2v*>(&fusedT[dd][(vox16 + ks*4)>>1]) = pk2;
    }
    __syncthreads();
#pragma unroll
    for (int rr=0; rr<4; ++rr){
      int dd = rr*16 + g4;
      float g = gateL[mm][dd];
      u4v xu = *reinterpret_cast<const u4v*>(&xt[mm][dd>>1][r4l*4]);
      u2v fu = *reinterpret_cast<const u2v*>(&fusedT[dd][r4l*2]);
      f4 o;
      float x0 = (dd&1) ? bh(xu[0]) : bl(xu[0]);
      float x1 = (dd&1) ? bh(xu[1]) : bl(xu[1]);
      float x2 = (dd&1) ? bh(xu[2]) : bl(xu[2]);
      float x3 = (dd&1) ? bh(xu[3]) : bl(xu[3]);
      o[0] = x0 + g*bl(fu.x);
      o[1] = x1 + g*bh(fu.x);
      o[2] = x2 + g*bl(fu.y);
      o[3] = x3 + g*bh(fu.y);
      *reinterpret_cast<f4*>(outp + (size_t)(mm*64+dd)*NVOX + V0 + r4l*4) = o;
    }
    __syncthreads();
  }
}

extern "C" void kernel_launch(void* const* d_in, const int* in_sizes, int n_in,
                              void* d_out, int out_size, void* d_ws, size_t ws_size,
                              hipStream_t stream){
  const float* x   = (const float*)d_in[0];
  const float* wq1 = (const float*)d_in[1];
  const float* bq1 = (const float*)d_in[2];
  const float* wq2 = (const float*)d_in[3];
  const float* bq2 = (const float*)d_in[4];
  const float* wa1 = (const float*)d_in[5];
  const float* ba1 = (const float*)d_in[6];
  const float* wa2 = (const float*)d_in[7];
  const float* ba2 = (const float*)d_in[8];
  const float* wf  = (const float*)d_in[9];
  const float* bfv = (const float*)d_in[10];
  const float* wg1 = (const float*)d_in[11];
  const float* bg1 = (const float*)d_in[12];
  const float* wg2 = (const float*)d_in[13];
  const float* bg2 = (const float*)d_in[14];
  float* outp = (float*)d_out;
  float* w = (float*)d_ws;
  float* dsums  = w;            // 16384 floats
  float* xbsums = w + 16384;    // 16384 floats
  float* wsa    = w + 32768;    // 256
  float* wsgate = w + 33024;    // 256
  float* wsqw   = w + 33280;    // 4
  float* wsinv  = w + 33284;    // 4
  unsigned short* wfb = (unsigned short*)(w + 33288);  // 4096 bf16 (2048 floats)
  float* partial = w + 35336;                          // 256*4096*8 floats = 32 MB
  size_t need = ((size_t)35336 + (size_t)256*4096*8) * sizeof(float);
  if (ws_size >= need){
    hipLaunchKernelGGL(k_pass1, dim3(4096), dim3(256), 0, stream, x, partial);
    hipLaunchKernelGGL(k_pass1b, dim3(256), dim3(256), 0, stream, partial, dsums, xbsums);
  } else {
    hipMemsetAsync(w, 0, 32768*sizeof(float), stream);
    hipLaunchKernelGGL(k_pass1_old, dim3(4096), dim3(256), 0, stream, x, dsums, xbsums);
  }
  hipLaunchKernelGGL(k_pass2, dim3(1), dim3(256), 0, stream, dsums, xbsums,
                     wq1,bq1,wq2,bq2,wa1,ba1,wa2,ba2,wf,bfv,wg1,bg1,wg2,bg2,
                     wsa, wsgate, wsqw, wsinv, wfb, outp);
  hipLaunchKernelGGL(k_pass3, dim3(4096), dim3(256), 0, stream, x, wfb, bfv,
                     wsa, wsgate, wsqw, wsinv, outp);
}

// Round 13
// 197.083 us; speedup vs baseline: 1.7713x; 1.7713x over previous
//
#include <hip/hip_runtime.h>
#include <math.h>

typedef __attribute__((ext_vector_type(4))) float f4;
typedef __attribute__((ext_vector_type(8))) short s8v;   // bf16x8 MFMA fragment
typedef __attribute__((ext_vector_type(4))) unsigned int u4v;
typedef __attribute__((ext_vector_type(2))) unsigned int u2v;

#define NVOX 262144        // 64^3
#define MB_TOT 67108864    // 4*64*NVOX

__device__ __forceinline__ float sigm(float x){ return 1.0f/(1.0f+expf(-x)); }
__device__ __forceinline__ unsigned short f2b(float f){
  unsigned x = __float_as_uint(f);
  return (unsigned short)((x + 0x7fffu + ((x>>16)&1u)) >> 16);
}
__device__ __forceinline__ unsigned cvtpk(float lo, float hi){
  unsigned r;
  asm("v_cvt_pk_bf16_f32 %0, %1, %2" : "=v"(r) : "v"(lo), "v"(hi));
  return r;
}
__device__ __forceinline__ float bl(unsigned u){ return __uint_as_float(u<<16); }
__device__ __forceinline__ float bh(unsigned u){ return __uint_as_float(u & 0xffff0000u); }

// ---------------- pass 1: r5 structure (best measured), split into 2 blocks/plane ----------------
// 512 blocks x 1024 threads; block = (mc = b>>1, half = b&1 -> rounds {2*half, 2*half+1}).
// r5 ran 256 blocks = 1 block/CU = 16 waves (grid-limited; VGPR=64, LDS=36KB allow 2).
// Same per-thread code -> same VGPR; 512 blocks -> 2 blocks/CU = 32 waves/CU.
// thread: chunk = tid&15 (z-quad), j = tid>>4. Wave-load = 1KB contiguous, batch-4.
__global__ __launch_bounds__(1024) void k_pass1(const float* __restrict__ x,
                                                float* __restrict__ dsums,
                                                float* __restrict__ xbsums){
  __shared__ float rowdat[8][1024];   // [ks0..3, wz0..3][row-in-round]  32 KB
  __shared__ float txb[32][16];       // [i-local][py*4+pz]
  __shared__ float tbs[32][16];       // [i-local][jq*4+kq]
  int tid = threadIdx.x;
  int b = blockIdx.x;
  int mc   = b >> 1;
  int half = b & 1;
  const float* xp = x + (size_t)mc * NVOX;
  int chunk = tid & 15;
  int rbase = tid >> 4;        // j, 0..63
  // per-thread z-weights (lzc uniform within a chunk)
  float wq0,wq1,wq2,wq3; int lzc;
  {
    float cz = fminf(fmaxf((chunk*4+0.5f)*0.0625f-0.5f, 0.0f), 3.0f);
    lzc = (int)cz;  wq0 = cz - (float)lzc;
    cz = fminf(fmaxf((chunk*4+1.5f)*0.0625f-0.5f, 0.0f), 3.0f); wq1 = cz - (float)lzc;
    cz = fminf(fmaxf((chunk*4+2.5f)*0.0625f-0.5f, 0.0f), 3.0f); wq2 = cz - (float)lzc;
    cz = fminf(fmaxf((chunk*4+3.5f)*0.0625f-0.5f, 0.0f), 3.0f); wq3 = cz - (float)lzc;
  }
  int kb = chunk >> 2;
  for (int r2=0; r2<2; ++r2){
    int round = half*2 + r2;
#pragma unroll
    for (int itg=0; itg<4; ++itg){
      f4 u[4];
#pragma unroll
      for (int s=0;s<4;++s){
        int it = itg*4+s;
        int row = round*1024 + it*64 + rbase;
        u[s] = *reinterpret_cast<const f4*>(xp + (size_t)row * 64 + chunk*4);
      }
#pragma unroll
      for (int s=0;s<4;++s){
        int it = itg*4+s;
        int rir = it*64 + rbase;         // row-in-round
        f4 v = u[s];
        float ksP = (v.x+v.y)+(v.z+v.w);
        float wB = v.x*wq0 + v.y*wq1 + v.z*wq2 + v.w*wq3;
        float wA = ksP - wB;
        // ks: reduce within 4-lane chunk groups (same z16 bucket)
        ksP += __shfl_xor(ksP, 1, 64);
        ksP += __shfl_xor(ksP, 2, 64);
        // wz: deposit into 4 regs, butterfly over the 16-lane (same-j) group
        float w0 = (lzc==0)?wA:0.f;
        float w1 = (lzc==1)?wA:((lzc==0)?wB:0.f);
        float w2 = (lzc==2)?wA:((lzc==1)?wB:0.f);
        float w3 = (lzc==3)?wA:((lzc==2)?wB:0.f);
#pragma unroll
        for (int mk=1; mk<16; mk<<=1){
          w0 += __shfl_xor(w0, mk, 64);
          w1 += __shfl_xor(w1, mk, 64);
          w2 += __shfl_xor(w2, mk, 64);
          w3 += __shfl_xor(w3, mk, 64);
        }
        if ((chunk&3)==0) rowdat[kb][rir] = ksP;
        if (chunk==0) rowdat[4][rir]=w0;
        if (chunk==1) rowdat[5][rir]=w1;
        if (chunk==2) rowdat[6][rir]=w2;
        if (chunk==3) rowdat[7][rir]=w3;
      }
    }
    __syncthreads();
    if (tid < 256){            // xb j-collapse: thread = (i_loc, py, pz)
      int il = tid>>4, py=(tid>>2)&3, pz=tid&3;
      int base = il*64;
      float s=0.f;
      for (int jj=0; jj<64; ++jj){
        int j = (jj + tid) & 63;         // bank stagger
        float cj = fminf(fmaxf((j+0.5f)*0.0625f-0.5f, 0.0f), 3.0f);
        int lj=(int)cj; float wj=cj-(float)lj;
        float w = (py==lj)?(1.f-wj):((py==lj+1)?wj:0.f);
        s += w * rowdat[4+pz][base+j];
      }
      txb[r2*16+il][py*4+pz] = s;
    } else if (tid < 512){     // bs j-collapse: thread = (i_loc, jq, kq)
      int u2 = tid-256;
      int il = u2>>4, jq=(u2>>2)&3, kq=u2&3;
      int base = il*64 + jq*16;
      float s=0.f;
      for (int jj=0; jj<16; ++jj) s += rowdat[kq][base + ((jj+u2)&15)];
      tbs[r2*16+il][jq*4+kq] = s;
    }
    __syncthreads();
  }
  if (tid < 64){               // xb i-collapse over this half's 32 i-rows
    int px = tid>>4, py=(tid>>2)&3, pz=tid&3;
    float s=0.f;
    for (int il=0; il<32; ++il){
      int i = half*32 + il;
      float ci = fminf(fmaxf((i+0.5f)*0.0625f-0.5f, 0.0f), 3.0f);
      int li=(int)ci; float wi=ci-(float)li;
      float w = (px==li)?(1.f-wi):((px==li+1)?wi:0.f);
      s += w * txb[il][py*4+pz];
    }
    atomicAdd(&xbsums[(size_t)mc*64+tid], s);
  } else if (tid < 96){        // bs i-collapse: 32 cells (iq in this half)
    int p_loc = tid-64;                  // 0..31
    int iq_loc = p_loc>>4, inner = p_loc&15;
    float s=0.f;
    for (int il=iq_loc*16; il<iq_loc*16+16; ++il) s += tbs[il][inner];
    atomicAdd(&dsums[(size_t)mc*64 + (half*2+iq_loc)*16 + inner], s);
  }
}

// ---------------- pass 2: all tiny MLPs (single block) + wf->bf16 conversion ----------------
__global__ __launch_bounds__(256) void k_pass2(
    const float* __restrict__ dsums, const float* __restrict__ xbsums,
    const float* __restrict__ wq1, const float* __restrict__ bq1,
    const float* __restrict__ wq2, const float* __restrict__ bq2,
    const float* __restrict__ wa1, const float* __restrict__ ba1,
    const float* __restrict__ wa2, const float* __restrict__ ba2,
    const float* __restrict__ wf,  const float* __restrict__ bfv,
    const float* __restrict__ wg1, const float* __restrict__ bg1,
    const float* __restrict__ wg2, const float* __restrict__ bg2,
    float* __restrict__ wsa, float* __restrict__ wsgate,
    float* __restrict__ wsqw, float* __restrict__ wsinv,
    unsigned short* __restrict__ wfb,
    float* __restrict__ outp)
{
  __shared__ float sGap[256];
  __shared__ float sA[256];
  __shared__ float sCm[256];
  __shared__ float sG[256];
  __shared__ float sGG[16];
  __shared__ float sQw[4];
  int tid = threadIdx.x;
  int m = tid>>6, c = tid&63;
  for (int t = tid; t < 4096; t += 256) wfb[t] = f2b(wf[t]);
  {
    float s=0.f;
    const float* dp = dsums + (size_t)tid*64;
    for (int p=0;p<64;++p) s += dp[p];
    sGap[tid] = s * (1.0f/262144.0f);
  }
  {
    int p = c;
    float h0=0,h1=0,h2=0,h3=0;
    for (int cc=0; cc<64; ++cc){
      float dm = dsums[((size_t)(m*64+cc))*64+p] * (1.0f/4096.0f);
      h0 += dm * wa1[0*64+cc];
      h1 += dm * wa1[1*64+cc];
      h2 += dm * wa1[2*64+cc];
      h3 += dm * wa1[3*64+cc];
    }
    h0 = fmaxf(h0 + ba1[0], 0.f);
    h1 = fmaxf(h1 + ba1[1], 0.f);
    h2 = fmaxf(h2 + ba1[2], 0.f);
    h3 = fmaxf(h3 + ba1[3], 0.f);
    float s = h0*wa2[0] + h1*wa2[1] + h2*wa2[2] + h3*wa2[3] + ba2[0];
    float aa = sigm(s);
    sA[tid] = aa;
    wsa[tid] = aa;
  }
  __syncthreads();
  if (tid < 4){
    int mm = tid;
    float q0=0,q1=0,q2=0,q3=0;
    for (int cc=0; cc<64; ++cc){
      float g = sGap[mm*64+cc];
      q0 += g*wq1[0*64+cc];
      q1 += g*wq1[1*64+cc];
      q2 += g*wq1[2*64+cc];
      q3 += g*wq1[3*64+cc];
    }
    q0 = fmaxf(q0+bq1[0],0.f); q1 = fmaxf(q1+bq1[1],0.f);
    q2 = fmaxf(q2+bq1[2],0.f); q3 = fmaxf(q3+bq1[3],0.f);
    float s0 = sigm(q0*wq2[0]+q1*wq2[1]+q2*wq2[2]+q3*wq2[3]+bq2[0]);
    float s1 = sigm(q0*wq2[4]+q1*wq2[5]+q2*wq2[6]+q3*wq2[7]+bq2[1]);
    sQw[mm] = 0.5f*(s0+s1);
    outp[MB_TOT + mm]     = s0;  // boundary
    outp[MB_TOT + 4 + mm] = s1;  // semantic
  }
  __syncthreads();
  float qw_m = sQw[m];
  float T = sQw[0]+sQw[1]+sQw[2]+sQw[3];
  float inv_m = 1.0f/(T - qw_m);
  if (tid < 4){ wsqw[tid] = sQw[tid]; wsinv[tid] = 1.0f/(T - sQw[tid]); }
  {
    const float* xbp = xbsums + (size_t)tid*64;
    float s=0.f;
    for (int p=0;p<64;++p) s += sA[m*64+p]*xbp[p];
    sCm[tid] = qw_m * s * (1.0f/262144.0f);
  }
  __syncthreads();
  {
    int dd = c;
    float acc=0.f;
    for (int cc=0; cc<64; ++cc){
      float Sm = sCm[0*64+cc]+sCm[1*64+cc]+sCm[2*64+cc]+sCm[3*64+cc];
      float em = (Sm - sCm[m*64+cc]) * inv_m;
      acc += em * wf[dd*64+cc];
    }
    sG[tid] = acc + bfv[dd];
  }
  __syncthreads();
  if (tid < 16){
    int mm = tid>>2, k = tid&3;
    float acc=0.f;
    for (int dd=0; dd<64; ++dd) acc += sG[mm*64+dd]*wg1[k*64+dd];
    sGG[tid] = fmaxf(acc + bg1[k], 0.f);
  }
  __syncthreads();
  {
    float s = sGG[m*4+0]*wg2[c*4+0] + sGG[m*4+1]*wg2[c*4+1]
            + sGG[m*4+2]*wg2[c*4+2] + sGG[m*4+3]*wg2[c*4+3] + bg2[c];
    wsgate[tid] = sigm(s);
  }
}

// ---------------- pass 3: coalesced fp32 staging + MFMA + coalesced transposed store ----------
__global__ __launch_bounds__(256) void k_pass3(
    const float* __restrict__ x, const unsigned short* __restrict__ wfb,
    const float* __restrict__ bfv,
    const float* __restrict__ wsa, const float* __restrict__ wsgate,
    const float* __restrict__ wsqw, const float* __restrict__ wsinv,
    float* __restrict__ outp)
{
  __shared__ unsigned int xt[4][32][68];     // [m][cc-pair][vox] bf16 pairs; 16B-aligned rows
  __shared__ unsigned int fusedT[64][34];    // [dd][vox-pair] bf16 pairs
  __shared__ float aCell[4][64];
  __shared__ float gateL[4][64];
  __shared__ __align__(16) float auq[4][64];
  __shared__ float bfL[64];
  __shared__ float A2[4][4];
  int tid = threadIdx.x;
  int b = 4095 - (int)blockIdx.x;     // reversed tile order (L3 reuse from pass1)
  int i = b >> 6, j = b & 63;
  size_t V0 = (size_t)b * 64;
  int w    = tid >> 6;
  int lane = tid & 63;
  int ks   = lane >> 4;
  int r    = lane & 15;
  int vox16 = w << 4;

  const float* xw = x + (size_t)(w*64)*NVOX + V0 + r*4;
  f4 v[16];
#pragma unroll
  for (int rr=0; rr<16; ++rr){
    int cc = ks*16 + rr;
    v[rr] = *reinterpret_cast<const f4*>(xw + (size_t)cc*NVOX);
  }
  aCell[w][lane] = wsa[tid];
  gateL[w][lane] = wsgate[tid];
  if (tid < 64) bfL[tid] = bfv[tid];
#pragma unroll
  for (int rr=0; rr<16; rr+=2){
    u4v pk;
#pragma unroll
    for (int q=0;q<4;++q) pk[q] = cvtpk(v[rr][q], v[rr+1][q]);
    *reinterpret_cast<u4v*>(&xt[w][ks*8 + (rr>>1)][r*4]) = pk;
  }
  __syncthreads();

  if (tid < 16){
    int mm = tid>>2, pz = tid&3;
    float ci = fminf(fmaxf((i+0.5f)*0.0625f-0.5f,0.f),3.f);
    int li=(int)ci; float wi=ci-(float)li; int hiI=li<3?li+1:3;
    float cj = fminf(fmaxf((j+0.5f)*0.0625f-0.5f,0.f),3.f);
    int lj=(int)cj; float wj=cj-(float)lj; int hj=lj<3?lj+1:3;
    A2[mm][pz] = (1.f-wi)*((1.f-wj)*aCell[mm][li*16+lj*4+pz] + wj*aCell[mm][li*16+hj*4+pz])
               + wi*((1.f-wj)*aCell[mm][hiI*16+lj*4+pz] + wj*aCell[mm][hiI*16+hj*4+pz]);
  }
  __syncthreads();
  {
    int mm = tid>>6, z = tid&63;
    float cz = fminf(fmaxf((z+0.5f)*0.0625f-0.5f,0.f),3.f);
    int lz=(int)cz; float wzf=cz-(float)lz; int hz=lz<3?lz+1:3;
    auq[mm][z] = ((1.f-wzf)*A2[mm][lz] + wzf*A2[mm][hz]) * wsqw[mm];
  }
  __syncthreads();

  s8v bfr[4][2];
#pragma unroll
  for (int t=0;t<4;++t)
#pragma unroll
    for (int kk=0;kk<2;++kk)
      bfr[t][kk] = *reinterpret_cast<const s8v*>(&wfb[(t*16 + r)*64 + kk*32 + ks*8]);

  f4 acc[4][4];
#pragma unroll
  for (int mm=0;mm<4;++mm)
#pragma unroll
    for (int t=0;t<4;++t) acc[mm][t] = f4{0.f,0.f,0.f,0.f};

#pragma unroll
  for (int mm=0;mm<4;++mm){
    union { unsigned int u[4]; s8v s; } A0, A1;
#pragma unroll
    for (int q=0;q<4;++q){
      A0.u[q] = xt[mm][ks*4+q][vox16+r];
      A1.u[q] = xt[mm][16+ks*4+q][vox16+r];
    }
#pragma unroll
    for (int t=0;t<4;++t){
      acc[mm][t] = __builtin_amdgcn_mfma_f32_16x16x32_bf16(A0.s, bfr[t][0], acc[mm][t], 0,0,0);
      acc[mm][t] = __builtin_amdgcn_mfma_f32_16x16x32_bf16(A1.s, bfr[t][1], acc[mm][t], 0,0,0);
    }
  }

  f4 aq[4]; float invv[4];
#pragma unroll
  for (int mm=0;mm<4;++mm){
    aq[mm]  = *reinterpret_cast<const f4*>(&auq[mm][vox16 + 4*ks]);
    invv[mm] = wsinv[mm];
  }
  f4 FS[4];
#pragma unroll
  for (int t=0;t<4;++t){
    FS[t] = f4{0.f,0.f,0.f,0.f};
#pragma unroll
    for (int mm=0;mm<4;++mm)
#pragma unroll
      for (int q=0;q<4;++q) FS[t][q] += aq[mm][q]*acc[mm][t][q];
  }

  int g4 = tid >> 4;
  int r4l = tid & 15;
#pragma unroll
  for (int mm=0;mm<4;++mm){
#pragma unroll
    for (int t=0;t<4;++t){
      int dd = t*16 + r;
      float bfvv = bfL[dd];
      float f0 = (FS[t][0] - aq[mm][0]*acc[mm][t][0])*invv[mm] + bfvv;
      float f1 = (FS[t][1] - aq[mm][1]*acc[mm][t][1])*invv[mm] + bfvv;
      float f2 = (FS[t][2] - aq[mm][2]*acc[mm][t][2])*invv[mm] + bfvv;
      float f3 = (FS[t][3] - aq[mm][3]*acc[mm][t][3])*invv[mm] + bfvv;
      u2v pk2;
      pk2.x = cvtpk(f0, f1);
      pk2.y = cvtpk(f2, f3);
      *reinterpret_cast<u2v*>(&fusedT[dd][(vox16 + ks*4)>>1]) = pk2;
    }
    __syncthreads();
#pragma unroll
    for (int rr=0; rr<4; ++rr){
      int dd = rr*16 + g4;
      float g = gateL[mm][dd];
      u4v xu = *reinterpret_cast<const u4v*>(&xt[mm][dd>>1][r4l*4]);
      u2v fu = *reinterpret_cast<const u2v*>(&fusedT[dd][r4l*2]);
      f4 o;
      float x0 = (dd&1) ? bh(xu[0]) : bl(xu[0]);
      float x1 = (dd&1) ? bh(xu[1]) : bl(xu[1]);
      float x2 = (dd&1) ? bh(xu[2]) : bl(xu[2]);
      float x3 = (dd&1) ? bh(xu[3]) : bl(xu[3]);
      o[0] = x0 + g*bl(fu.x);
      o[1] = x1 + g*bh(fu.x);
      o[2] = x2 + g*bl(fu.y);
      o[3] = x3 + g*bh(fu.y);
      *reinterpret_cast<f4*>(outp + (size_t)(mm*64+dd)*NVOX + V0 + r4l*4) = o;
    }
    __syncthreads();
  }
}

extern "C" void kernel_launch(void* const* d_in, const int* in_sizes, int n_in,
                              void* d_out, int out_size, void* d_ws, size_t ws_size,
                              hipStream_t stream){
  const float* x   = (const float*)d_in[0];
  const float* wq1 = (const float*)d_in[1];
  const float* bq1 = (const float*)d_in[2];
  const float* wq2 = (const float*)d_in[3];
  const float* bq2 = (const float*)d_in[4];
  const float* wa1 = (const float*)d_in[5];
  const float* ba1 = (const float*)d_in[6];
  const float* wa2 = (const float*)d_in[7];
  const float* ba2 = (const float*)d_in[8];
  const float* wf  = (const float*)d_in[9];
  const float* bfv = (const float*)d_in[10];
  const float* wg1 = (const float*)d_in[11];
  const float* bg1 = (const float*)d_in[12];
  const float* wg2 = (const float*)d_in[13];
  const float* bg2 = (const float*)d_in[14];
  float* outp = (float*)d_out;
  float* w = (float*)d_ws;
  float* dsums  = w;            // 16384 floats
  float* xbsums = w + 16384;    // 16384 floats
  float* wsa    = w + 32768;    // 256
  float* wsgate = w + 33024;    // 256
  float* wsqw   = w + 33280;    // 4
  float* wsinv  = w + 33284;    // 4
  unsigned short* wfb = (unsigned short*)(w + 33288);  // 4096 bf16
  hipMemsetAsync(w, 0, 32768*sizeof(float), stream);
  hipLaunchKernelGGL(k_pass1, dim3(512), dim3(1024), 0, stream, x, dsums, xbsums);
  hipLaunchKernelGGL(k_pass2, dim3(1), dim3(256), 0, stream, dsums, xbsums,
                     wq1,bq1,wq2,bq2,wa1,ba1,wa2,ba2,wf,bfv,wg1,bg1,wg2,bg2,
                     wsa, wsgate, wsqw, wsinv, wfb, outp);
  hipLaunchKernelGGL(k_pass3, dim3(4096), dim3(256), 0, stream, x, wfb, bfv,
                     wsa, wsgate, wsqw, wsinv, outp);
}